// Round 4
// baseline (563.937 us; speedup 1.0000x reference)
//
#include <hip/hip_runtime.h>

#define NWIN 2048
#define NTOK 64
#define CDIM 256
#define NH 8
#define HD 32
#define QSCALE 0.17677669529663689f   // 32^-0.5

// LDS stride for x / attn_out tiles (bf16 units): 264 -> row stride 528 B =
// 132 words; 132 mod 32 = 4 -> 2-way on b128 access (free, m136).
#define LDA 264
// LDS stride for the mask tile (f32 units): 68 -> 2-way on float4 reads (free).
#define LDM 68

typedef __bf16 bf16x8 __attribute__((ext_vector_type(8)));
typedef float  f32x4  __attribute__((ext_vector_type(4)));
typedef unsigned int u32x4 __attribute__((ext_vector_type(4)));

__device__ __forceinline__ unsigned short f2bf(float f) {
    union { float f; unsigned u; } v; v.f = f;
    unsigned r = v.u + 0x7FFFu + ((v.u >> 16) & 1u);   // RNE
    return (unsigned short)(r >> 16);
}

__device__ __forceinline__ bf16x8 ld16(const unsigned short* p) {
    return *(const bf16x8*)p;
}

__device__ __forceinline__ unsigned cvtpk(float lo, float hi) {
    unsigned r;
    asm("v_cvt_pk_bf16_f32 %0, %1, %2" : "=v"(r) : "v"(lo), "v"(hi));
    return r;
}
__device__ __forceinline__ void pl32(unsigned &a, unsigned &b) {
    asm("v_permlane32_swap_b32 %0, %1" : "+v"(a), "+v"(b));
}
__device__ __forceinline__ void pl16(unsigned &a, unsigned &b) {
    asm("v_permlane16_swap_b32 %0, %1" : "+v"(a), "+v"(b));
}

// In-register C-layout -> A/B-frag exchange over a 32-long axis (verified r1-r3).
__device__ __forceinline__ bf16x8 xchg32(f32x4 t0, f32x4 t1) {
    unsigned u00 = cvtpk(t0[0], t0[1]);
    unsigned u01 = cvtpk(t0[2], t0[3]);
    unsigned u10 = cvtpk(t1[0], t1[1]);
    unsigned u11 = cvtpk(t1[2], t1[3]);
    pl32(u00, u10);
    pl32(u01, u11);
    pl16(u00, u10);
    pl16(u01, u11);
    union { u32x4 u; bf16x8 v; } r;
    r.u = (u32x4){u00, u01, u10, u11};
    return r.v;
}

// ---- precast: weights fp32->bf16; bias_table -> relbQ[h][q][k] fp32 ----
__global__ void precast_kernel(const float* __restrict__ wq, const float* __restrict__ wp,
                               const float* __restrict__ bt,
                               unsigned short* __restrict__ wqb, unsigned short* __restrict__ wpb,
                               float* __restrict__ relbQ) {
    int i = blockIdx.x * 256 + threadIdx.x;
    if (i < 196608) {
        wqb[i] = f2bf(wq[i]);
    } else if (i < 262144) {
        wpb[i - 196608] = f2bf(wp[i - 196608]);
    } else if (i < 294912) {
        int j = i - 262144;            // h*4096 + q*64 + k
        int h = j >> 12;
        int q = (j >> 6) & 63;
        int k = j & 63;
        int yq = q >> 3, xq = q & 7, yk = k >> 3, xk = k & 7;
        int idx = (yq - yk + 7) * 15 + (xq - xk + 7);
        relbQ[j] = bt[idx * NH + h];
    }
}

// Transposed projection pass: NT token-tiles starting at row0, 32 features.
// Output frags: (token = nt*16+lm, d = quad*8..+8). Peak live: 2*NT accs +
// NT staging + 2 w-frags -> fits the 128-reg budget for NT<=4.
template<int NT>
__device__ __forceinline__ void proj_passT(const unsigned short* sA, int row0,
                                           const unsigned short* wrow0, const unsigned short* wrow1,
                                           const float* bias0, float scale, int lm, int quad,
                                           bf16x8 outf[NT]) {
    const f32x4 fzero = {0.f, 0.f, 0.f, 0.f};
    f32x4 a0[NT], a1[NT];
    #pragma unroll
    for (int nt = 0; nt < NT; ++nt) { a0[nt] = fzero; a1[nt] = fzero; }

    #pragma unroll
    for (int ks = 0; ks < 8; ++ks) {
        bf16x8 xa[NT];
        #pragma unroll
        for (int nt = 0; nt < NT; ++nt)
            xa[nt] = ld16(sA + (row0 + nt * 16 + lm) * LDA + ks * 32 + quad * 8);
        bf16x8 wf0 = ld16(wrow0 + ks * 32 + quad * 8);
        bf16x8 wf1 = ld16(wrow1 + ks * 32 + quad * 8);
        #pragma unroll
        for (int nt = 0; nt < NT; ++nt) {
            a0[nt] = __builtin_amdgcn_mfma_f32_16x16x32_bf16(wf0, xa[nt], a0[nt], 0, 0, 0);
            a1[nt] = __builtin_amdgcn_mfma_f32_16x16x32_bf16(wf1, xa[nt], a1[nt], 0, 0, 0);
        }
    }

    const float4 b0 = *(const float4*)(bias0 + quad * 4);
    const float4 b1 = *(const float4*)(bias0 + 16 + quad * 4);
    const float b0v[4] = {b0.x, b0.y, b0.z, b0.w};
    const float b1v[4] = {b1.x, b1.y, b1.z, b1.w};
    #pragma unroll
    for (int nt = 0; nt < NT; ++nt) {
        #pragma unroll
        for (int r = 0; r < 4; ++r) {
            a0[nt][r] = (a0[nt][r] + b0v[r]) * scale;
            a1[nt][r] = (a1[nt][r] + b1v[r]) * scale;
        }
        outf[nt] = xchg32(a0[nt], a1[nt]);
    }
}

// 1024 threads = 16 waves: wave (h, half) handles head h = wv>>1, query rows
// [qh, qh+32). Per-wave register state halves vs. the 8-wave version (r3 used
// ~192 unified regs -> only 8 waves/CU fit the 2048-reg pool). K/V frags are
// duplicated across the wave pair (compute is cheap; latency is not).
__global__ __launch_bounds__(1024, 4)
void win_attn_kernel(const float* __restrict__ x, const float* __restrict__ mask,
                     const float* __restrict__ bq, const float* __restrict__ bp,
                     const unsigned short* __restrict__ wq, const unsigned short* __restrict__ wp,
                     const float* __restrict__ relbQ, float* __restrict__ out) {
    // 67,584 B bf16 tiles + 17,408 B mask tile = 84,992 B of LDS
    __shared__ __align__(16) unsigned char smraw[2 * NTOK * LDA * 2 + NTOK * LDM * 4];
    unsigned short* sA = (unsigned short*)smraw;               // x (bf16)
    unsigned short* sO = sA + NTOK * LDA;                      // attn_out (bf16)
    float*          sM = (float*)(smraw + 2 * NTOK * LDA * 2); // mask (f32)

    const int b    = blockIdx.x;
    const int tid  = threadIdx.x;
    const int wv   = tid >> 6;            // 0..15
    const int lane = tid & 63;
    const int lm   = lane & 15;
    const int quad = lane >> 4;
    const f32x4 fzero = {0.f, 0.f, 0.f, 0.f};

    // ---------- Phase 0: stage x (fp32->bf16) and mask (f32) into LDS ----------
    {
        const int row = tid >> 4;             // 64 rows, 16 threads/row
        const int c0  = (tid & 15) * 16;
        const float4* gx = (const float4*)(x + ((size_t)b * NTOK + row) * CDIM + c0);
        unsigned short* dst = sA + row * LDA + c0;
        #pragma unroll
        for (int i = 0; i < 2; ++i) {
            float4 a = gx[2 * i];
            float4 c = gx[2 * i + 1];
            u32x4 w = { cvtpk(a.x, a.y), cvtpk(a.z, a.w), cvtpk(c.x, c.y), cvtpk(c.z, c.w) };
            *(u32x4*)(dst + i * 8) = w;
        }
        // mask: 64 x 64 f32, 4 f32 per thread
        const int mc0 = (tid & 15) * 4;
        float4 m0 = *(const float4*)(mask + (size_t)b * (NTOK * NTOK) + row * 64 + mc0);
        *(float4*)(sM + row * LDM + mc0) = m0;
    }
    __syncthreads();

    const int h  = wv >> 1;
    const int qh = (wv & 1) * 32;         // this wave's query-half

    // ---------- Phase 1: projections (transposed QK trick, r1-verified) ----------
    bf16x8 kf[4];     // K A-frags, all 64 keys (duplicated per wave pair)
    bf16x8 qf[2];     // Q B-frags, this wave's 32 queries
    bf16x8 vf[2][2];  // V^T A-frags, all 64 keys (duplicated)

    proj_passT<4>(sA, 0,  wq + (CDIM + h*HD + lm) * CDIM, wq + (CDIM + h*HD + 16 + lm) * CDIM,
                  bq + CDIM + h*HD, 1.0f, lm, quad, kf);
    proj_passT<2>(sA, qh, wq + (h*HD + lm) * CDIM, wq + (h*HD + 16 + lm) * CDIM,
                  bq + h*HD, QSCALE, lm, quad, qf);

    #pragma unroll
    for (int t = 0; t < 2; ++t) {
        f32x4 va[4];
        #pragma unroll
        for (int mt = 0; mt < 4; ++mt) va[mt] = fzero;
        const unsigned short* wvp = wq + (2*CDIM + h*HD + t*16 + lm) * CDIM;
        #pragma unroll
        for (int ks = 0; ks < 8; ++ks) {
            bf16x8 xa[4];
            #pragma unroll
            for (int mt = 0; mt < 4; ++mt)
                xa[mt] = ld16(sA + (mt * 16 + lm) * LDA + ks * 32 + quad * 8);
            bf16x8 wfv = ld16(wvp + ks * 32 + quad * 8);
            #pragma unroll
            for (int mt = 0; mt < 4; ++mt)
                va[mt] = __builtin_amdgcn_mfma_f32_16x16x32_bf16(xa[mt], wfv, va[mt], 0, 0, 0);
        }
        const float bV = bq[2*CDIM + h*HD + t*16 + lm];
        #pragma unroll
        for (int mt = 0; mt < 4; ++mt)
            #pragma unroll
            for (int r = 0; r < 4; ++r) va[mt][r] += bV;
        vf[t][0] = xchg32(va[0], va[1]);   // keys  0..31
        vf[t][1] = xchg32(va[2], va[3]);   // keys 32..63
    }

    // ---------- Phase 2: attention for this wave's 32 queries ----------
    {
        const float* relh = relbQ + h * (NTOK * NTOK);

        #pragma unroll
        for (int rc = 0; rc < 2; ++rc) {
            const int qrow = qh + rc * 16;
            // S^T chunk: col = query (lm), row = key 4*quad+reg+16*jt
            f32x4 s[4];
            #pragma unroll
            for (int jt = 0; jt < 4; ++jt)
                s[jt] = __builtin_amdgcn_mfma_f32_16x16x32_bf16(kf[jt], qf[rc], fzero, 0, 0, 0);

            const float* mrow = sM   + (qrow + lm) * LDM;
            const float* rrow = relh + (qrow + lm) * 64;
            #pragma unroll
            for (int jt = 0; jt < 4; ++jt) {
                float4 rb = *(const float4*)(rrow + jt * 16 + quad * 4);
                float4 mk = *(const float4*)(mrow + jt * 16 + quad * 4);
                const float rbv[4] = {rb.x, rb.y, rb.z, rb.w};
                const float mkv[4] = {mk.x, mk.y, mk.z, mk.w};
                #pragma unroll
                for (int r = 0; r < 4; ++r) s[jt][r] += rbv[r] + mkv[r];
            }

            // softmax over keys: 14 in-lane max + 2 cross-quad shuffles
            float mx = s[0][0];
            #pragma unroll
            for (int jt = 0; jt < 4; ++jt)
                #pragma unroll
                for (int r = 0; r < 4; ++r) mx = fmaxf(mx, s[jt][r]);
            mx = fmaxf(mx, __shfl_xor(mx, 16, 64));
            mx = fmaxf(mx, __shfl_xor(mx, 32, 64));

            float sum = 0.f;
            #pragma unroll
            for (int jt = 0; jt < 4; ++jt)
                #pragma unroll
                for (int r = 0; r < 4; ++r) {
                    float e = __expf(s[jt][r] - mx);
                    s[jt][r] = e;
                    sum += e;
                }
            sum += __shfl_xor(sum, 16, 64);
            sum += __shfl_xor(sum, 32, 64);
            const float inv = 1.0f / sum;   // defer row scaling to PV output

            // P^T B-frags via exchange over key axis
            bf16x8 pb0 = xchg32(s[0], s[1]);   // keys  0..31
            bf16x8 pb1 = xchg32(s[2], s[3]);   // keys 32..63

            // O^T = V^T . P^T : col = query (lm), row = d 4*quad+reg (+16*dt)
            f32x4 o0 = __builtin_amdgcn_mfma_f32_16x16x32_bf16(vf[0][0], pb0, fzero, 0, 0, 0);
            o0 = __builtin_amdgcn_mfma_f32_16x16x32_bf16(vf[0][1], pb1, o0, 0, 0, 0);
            f32x4 o1 = __builtin_amdgcn_mfma_f32_16x16x32_bf16(vf[1][0], pb0, fzero, 0, 0, 0);
            o1 = __builtin_amdgcn_mfma_f32_16x16x32_bf16(vf[1][1], pb1, o1, 0, 0, 0);
            #pragma unroll
            for (int r = 0; r < 4; ++r) { o0[r] *= inv; o1[r] *= inv; }

            // exchange over d axis -> (token = qrow+lm, d = quad*8..+8)
            bf16x8 ob = xchg32(o0, o1);
            *(bf16x8*)(sO + (qrow + lm) * LDA + h * HD + quad * 8) = ob;
        }
    }
    __syncthreads();   // attn_out complete

    // ---------- Phase 3: out = attn_out @ wp^T + bp ----------
    // wave wv: rows [(wv&1)*32, +32), cols [(wv>>1)*32, +32)
    {
        const int r0 = (wv & 1) * 32;
        const int n0 = (wv >> 1) * HD;
        f32x4 acc[2][2];
        #pragma unroll
        for (int mt = 0; mt < 2; ++mt) { acc[mt][0] = fzero; acc[mt][1] = fzero; }

        #pragma unroll
        for (int ks = 0; ks < 8; ++ks) {
            bf16x8 bfr[2];
            #pragma unroll
            for (int nt = 0; nt < 2; ++nt)
                bfr[nt] = ld16(wp + (n0 + nt * 16 + lm) * CDIM + ks * 32 + quad * 8);
            bf16x8 afr[2];
            #pragma unroll
            for (int mt = 0; mt < 2; ++mt)
                afr[mt] = ld16(sO + (r0 + mt * 16 + lm) * LDA + ks * 32 + quad * 8);
            #pragma unroll
            for (int mt = 0; mt < 2; ++mt)
                #pragma unroll
                for (int nt = 0; nt < 2; ++nt)
                    acc[mt][nt] = __builtin_amdgcn_mfma_f32_16x16x32_bf16(afr[mt], bfr[nt], acc[mt][nt], 0, 0, 0);
        }

        float bpv[2] = { bp[n0 + lm], bp[n0 + 16 + lm] };
        #pragma unroll
        for (int mt = 0; mt < 2; ++mt)
            #pragma unroll
            for (int nt = 0; nt < 2; ++nt)
                #pragma unroll
                for (int reg = 0; reg < 4; ++reg) {
                    int r = r0 + mt * 16 + quad * 4 + reg;
                    out[((size_t)b * NTOK + r) * CDIM + n0 + nt * 16 + lm] = acc[mt][nt][reg] + bpv[nt];
                }
    }
}

extern "C" void kernel_launch(void* const* d_in, const int* in_sizes, int n_in,
                              void* d_out, int out_size, void* d_ws, size_t ws_size,
                              hipStream_t stream) {
    const float* x    = (const float*)d_in[0];
    const float* mask = (const float*)d_in[1];
    const float* wq   = (const float*)d_in[2];
    const float* bq   = (const float*)d_in[3];
    const float* wp   = (const float*)d_in[4];
    const float* bp   = (const float*)d_in[5];
    const float* bt   = (const float*)d_in[6];

    unsigned short* wqb   = (unsigned short*)d_ws;              // 768x256 bf16
    unsigned short* wpb   = wqb + 196608;                        // 256x256 bf16
    float*          relbQ = (float*)((char*)d_ws + 524288);     // 8x64x64 fp32 (h, q, k)
    float*          out   = (float*)d_out;

    precast_kernel<<<1152, 256, 0, stream>>>(wq, wp, bt, wqb, wpb, relbQ);
    win_attn_kernel<<<NWIN, 1024, 0, stream>>>(x, mask, bq, bp, wqb, wpb, relbQ, out);
}

// Round 6
// 461.101 us; speedup vs baseline: 1.2230x; 1.2230x over previous
//
#include <hip/hip_runtime.h>

#define NWIN 2048
#define NTOK 64
#define CDIM 256
#define NH 8
#define HD 32
#define QSCALE 0.17677669529663689f   // 32^-0.5

// LDS stride for x / attn_out tiles (bf16 units): 264 -> row stride 528 B =
// 132 words; 132 mod 32 = 4 -> 2-way on b128 access (free, m136).
#define LDA 264

typedef __bf16 bf16x8 __attribute__((ext_vector_type(8)));
typedef float  f32x4  __attribute__((ext_vector_type(4)));
typedef unsigned int u32x4 __attribute__((ext_vector_type(4)));

__device__ __forceinline__ unsigned short f2bf(float f) {
    union { float f; unsigned u; } v; v.f = f;
    unsigned r = v.u + 0x7FFFu + ((v.u >> 16) & 1u);   // RNE
    return (unsigned short)(r >> 16);
}

__device__ __forceinline__ bf16x8 ld16(const unsigned short* p) {
    return *(const bf16x8*)p;
}

__device__ __forceinline__ unsigned cvtpk(float lo, float hi) {
    unsigned r;
    asm("v_cvt_pk_bf16_f32 %0, %1, %2" : "=v"(r) : "v"(lo), "v"(hi));
    return r;
}
__device__ __forceinline__ void pl32(unsigned &a, unsigned &b) {
    asm("v_permlane32_swap_b32 %0, %1" : "+v"(a), "+v"(b));
}
__device__ __forceinline__ void pl16(unsigned &a, unsigned &b) {
    asm("v_permlane16_swap_b32 %0, %1" : "+v"(a), "+v"(b));
}

// In-register C-layout -> A/B-frag exchange over a 32-long axis (verified r1-r4).
__device__ __forceinline__ bf16x8 xchg32(f32x4 t0, f32x4 t1) {
    unsigned u00 = cvtpk(t0[0], t0[1]);
    unsigned u01 = cvtpk(t0[2], t0[3]);
    unsigned u10 = cvtpk(t1[0], t1[1]);
    unsigned u11 = cvtpk(t1[2], t1[3]);
    pl32(u00, u10);
    pl32(u01, u11);
    pl16(u00, u10);
    pl16(u01, u11);
    union { u32x4 u; bf16x8 v; } r;
    r.u = (u32x4){u00, u01, u10, u11};
    return r.v;
}

// ---- precast: weights fp32->bf16; bias_table -> relbQ[h][q][k] fp32 ----
__global__ void precast_kernel(const float* __restrict__ wq, const float* __restrict__ wp,
                               const float* __restrict__ bt,
                               unsigned short* __restrict__ wqb, unsigned short* __restrict__ wpb,
                               float* __restrict__ relbQ) {
    int i = blockIdx.x * 256 + threadIdx.x;
    if (i < 196608) {
        wqb[i] = f2bf(wq[i]);
    } else if (i < 262144) {
        wpb[i - 196608] = f2bf(wp[i - 196608]);
    } else if (i < 294912) {
        int j = i - 262144;            // h*4096 + q*64 + k
        int h = j >> 12;
        int q = (j >> 6) & 63;
        int k = j & 63;
        int yq = q >> 3, xq = q & 7, yk = k >> 3, xk = k & 7;
        int idx = (yq - yk + 7) * 15 + (xq - xk + 7);
        relbQ[j] = bt[idx * NH + h];
    }
}

// 512 threads = 8 waves, wave = head (r3 structure: no K/V duplication).
// Register plan for the 128-unified / 64-arch budget of (512,4):
//   - K frags are NOT persistent: computed, stored to LDS (4 KB/head),
//     re-loaded 16 B at a time in phase 2.
//   - persistent arch frags: qf[4] (16) + vf[2][2] (16) = 32.
//   - sO overlays sX (x dead after phase 1) -> LDS 66.5 KB -> 2 blocks/CU.
__global__ __launch_bounds__(512, 4)
void win_attn_kernel(const float* __restrict__ x, const float* __restrict__ mask,
                     const float* __restrict__ bq, const float* __restrict__ bp,
                     const unsigned short* __restrict__ wq, const unsigned short* __restrict__ wp,
                     const float* __restrict__ relbQ, float* __restrict__ out) {
    // 33,792 B x/attn_out (overlaid) + 32,768 B K frags = 66,560 B
    __shared__ __align__(16) unsigned short sm[NTOK * LDA + NH * 4 * 64 * 8];
    unsigned short* sX = sm;                  // x (bf16) during phase 1; attn_out after
    unsigned short* sK = sm + NTOK * LDA;     // K frags: [(h*4+jt)*64+lane]*8 ushorts

    const int b    = blockIdx.x;
    const int tid  = threadIdx.x;
    const int wv   = tid >> 6;            // wave id == head id
    const int lane = tid & 63;
    const int lm   = lane & 15;
    const int quad = lane >> 4;
    const f32x4 fzero = {0.f, 0.f, 0.f, 0.f};

    // ---------- Phase 0: stage x window, fp32 -> bf16 ----------
    {
        const int row = tid >> 3;             // 64 rows, 8 threads/row
        const int c0  = (tid & 7) * 32;
        const float4* gx = (const float4*)(x + ((size_t)b * NTOK + row) * CDIM + c0);
        unsigned short* dst = sX + row * LDA + c0;
        #pragma unroll
        for (int i = 0; i < 4; ++i) {
            float4 a = gx[2 * i];
            float4 c = gx[2 * i + 1];
            u32x4 w = { cvtpk(a.x, a.y), cvtpk(a.z, a.w), cvtpk(c.x, c.y), cvtpk(c.z, c.w) };
            *(u32x4*)(dst + i * 8) = w;
        }
    }
    __syncthreads();

    const int h = wv;

    // ---------- Phase 1a: K^T = W_k . x^T ; frags go straight to LDS ----------
    {
        f32x4 a0[4], a1[4];
        #pragma unroll
        for (int nt = 0; nt < 4; ++nt) { a0[nt] = fzero; a1[nt] = fzero; }
        const unsigned short* w0 = wq + (CDIM + h*HD + lm) * CDIM;
        const unsigned short* w1 = wq + (CDIM + h*HD + 16 + lm) * CDIM;
        #pragma unroll
        for (int ks = 0; ks < 8; ++ks) {
            bf16x8 xa[4];
            #pragma unroll
            for (int nt = 0; nt < 4; ++nt)
                xa[nt] = ld16(sX + (nt * 16 + lm) * LDA + ks * 32 + quad * 8);
            bf16x8 wf0 = ld16(w0 + ks * 32 + quad * 8);
            bf16x8 wf1 = ld16(w1 + ks * 32 + quad * 8);
            #pragma unroll
            for (int nt = 0; nt < 4; ++nt) {
                a0[nt] = __builtin_amdgcn_mfma_f32_16x16x32_bf16(wf0, xa[nt], a0[nt], 0, 0, 0);
                a1[nt] = __builtin_amdgcn_mfma_f32_16x16x32_bf16(wf1, xa[nt], a1[nt], 0, 0, 0);
            }
        }
        const float4 b0 = *(const float4*)(bq + CDIM + h*HD + quad*4);
        const float4 b1 = *(const float4*)(bq + CDIM + h*HD + 16 + quad*4);
        const float b0v[4] = {b0.x, b0.y, b0.z, b0.w};
        const float b1v[4] = {b1.x, b1.y, b1.z, b1.w};
        #pragma unroll
        for (int nt = 0; nt < 4; ++nt) {
            #pragma unroll
            for (int r = 0; r < 4; ++r) { a0[nt][r] += b0v[r]; a1[nt][r] += b1v[r]; }
            bf16x8 kfrag = xchg32(a0[nt], a1[nt]);
            *(bf16x8*)(sK + ((h * 4 + nt) * 64 + lane) * 8) = kfrag;   // contiguous, conflict-free
        }
    }

    // ---------- Phase 1b: Q^T = W_q . x^T (persistent qf[4]) ----------
    bf16x8 qf[4];     // Q B-frags: (query = nt*16+lm, d = quad*8..+8)
    {
        f32x4 a0[4], a1[4];
        #pragma unroll
        for (int nt = 0; nt < 4; ++nt) { a0[nt] = fzero; a1[nt] = fzero; }
        const unsigned short* w0 = wq + (h*HD + lm) * CDIM;
        const unsigned short* w1 = wq + (h*HD + 16 + lm) * CDIM;
        #pragma unroll
        for (int ks = 0; ks < 8; ++ks) {
            bf16x8 xa[4];
            #pragma unroll
            for (int nt = 0; nt < 4; ++nt)
                xa[nt] = ld16(sX + (nt * 16 + lm) * LDA + ks * 32 + quad * 8);
            bf16x8 wf0 = ld16(w0 + ks * 32 + quad * 8);
            bf16x8 wf1 = ld16(w1 + ks * 32 + quad * 8);
            #pragma unroll
            for (int nt = 0; nt < 4; ++nt) {
                a0[nt] = __builtin_amdgcn_mfma_f32_16x16x32_bf16(wf0, xa[nt], a0[nt], 0, 0, 0);
                a1[nt] = __builtin_amdgcn_mfma_f32_16x16x32_bf16(wf1, xa[nt], a1[nt], 0, 0, 0);
            }
        }
        const float4 b0 = *(const float4*)(bq + h*HD + quad*4);
        const float4 b1 = *(const float4*)(bq + h*HD + 16 + quad*4);
        const float b0v[4] = {b0.x, b0.y, b0.z, b0.w};
        const float b1v[4] = {b1.x, b1.y, b1.z, b1.w};
        #pragma unroll
        for (int nt = 0; nt < 4; ++nt) {
            #pragma unroll
            for (int r = 0; r < 4; ++r) {
                a0[nt][r] = (a0[nt][r] + b0v[r]) * QSCALE;
                a1[nt][r] = (a1[nt][r] + b1v[r]) * QSCALE;
            }
            qf[nt] = xchg32(a0[nt], a1[nt]);
        }
    }

    // ---------- Phase 1c: V = x . Wv^T (persistent vf[2][2]) ----------
    bf16x8 vf[2][2];  // V^T A-frags: (d = t*16+lm, key = kk*32 + quad*8..+8)
    #pragma unroll
    for (int t = 0; t < 2; ++t) {
        f32x4 va[4];
        #pragma unroll
        for (int mt = 0; mt < 4; ++mt) va[mt] = fzero;
        const unsigned short* wvp = wq + (2*CDIM + h*HD + t*16 + lm) * CDIM;
        #pragma unroll
        for (int ks = 0; ks < 8; ++ks) {
            bf16x8 xa[4];
            #pragma unroll
            for (int mt = 0; mt < 4; ++mt)
                xa[mt] = ld16(sX + (mt * 16 + lm) * LDA + ks * 32 + quad * 8);
            bf16x8 wfv = ld16(wvp + ks * 32 + quad * 8);
            #pragma unroll
            for (int mt = 0; mt < 4; ++mt)
                va[mt] = __builtin_amdgcn_mfma_f32_16x16x32_bf16(xa[mt], wfv, va[mt], 0, 0, 0);
        }
        const float bV = bq[2*CDIM + h*HD + t*16 + lm];
        #pragma unroll
        for (int mt = 0; mt < 4; ++mt)
            #pragma unroll
            for (int r = 0; r < 4; ++r) va[mt][r] += bV;
        vf[t][0] = xchg32(va[0], va[1]);   // keys  0..31
        vf[t][1] = xchg32(va[2], va[3]);   // keys 32..63
    }
    __syncthreads();   // all sX reads done (sO overlays sX); sK visible

    // ---------- Phase 2: attention; K frags from LDS; mask/rel from global ----------
    {
        const float* maskb = mask + (size_t)b * (NTOK * NTOK);
        const float* relh  = relbQ + h * (NTOK * NTOK);
        const unsigned short* sKh = sK + h * 4 * 64 * 8;

        #pragma unroll
        for (int rc = 0; rc < 4; ++rc) {
            // S^T chunk: col = query (lm), row = key 4*quad+reg+16*jt
            f32x4 s[4];
            #pragma unroll
            for (int jt = 0; jt < 4; ++jt) {
                bf16x8 kf = ld16(sKh + (jt * 64 + lane) * 8);
                s[jt] = __builtin_amdgcn_mfma_f32_16x16x32_bf16(kf, qf[rc], fzero, 0, 0, 0);
            }

            const float* mrow = maskb + (rc * 16 + lm) * 64;
            const float* rrow = relh  + (rc * 16 + lm) * 64;
            #pragma unroll
            for (int jt = 0; jt < 4; ++jt) {
                float4 rb = *(const float4*)(rrow + jt * 16 + quad * 4);
                float4 mk = *(const float4*)(mrow + jt * 16 + quad * 4);
                const float rbv[4] = {rb.x, rb.y, rb.z, rb.w};
                const float mkv[4] = {mk.x, mk.y, mk.z, mk.w};
                #pragma unroll
                for (int r = 0; r < 4; ++r) s[jt][r] += rbv[r] + mkv[r];
            }

            // softmax over keys: in-lane + 2 cross-quad shuffles
            float mx = s[0][0];
            #pragma unroll
            for (int jt = 0; jt < 4; ++jt)
                #pragma unroll
                for (int r = 0; r < 4; ++r) mx = fmaxf(mx, s[jt][r]);
            mx = fmaxf(mx, __shfl_xor(mx, 16, 64));
            mx = fmaxf(mx, __shfl_xor(mx, 32, 64));

            float sum = 0.f;
            #pragma unroll
            for (int jt = 0; jt < 4; ++jt)
                #pragma unroll
                for (int r = 0; r < 4; ++r) {
                    float e = __expf(s[jt][r] - mx);
                    s[jt][r] = e;
                    sum += e;
                }
            sum += __shfl_xor(sum, 16, 64);
            sum += __shfl_xor(sum, 32, 64);
            const float inv = 1.0f / sum;   // defer row scaling to PV output

            // P^T B-frags via exchange over key axis
            bf16x8 pb0 = xchg32(s[0], s[1]);   // keys  0..31
            bf16x8 pb1 = xchg32(s[2], s[3]);   // keys 32..63

            // O^T = V^T . P^T : col = query (lm), row = d 4*quad+reg (+16*dt)
            f32x4 o0 = __builtin_amdgcn_mfma_f32_16x16x32_bf16(vf[0][0], pb0, fzero, 0, 0, 0);
            o0 = __builtin_amdgcn_mfma_f32_16x16x32_bf16(vf[0][1], pb1, o0, 0, 0, 0);
            f32x4 o1 = __builtin_amdgcn_mfma_f32_16x16x32_bf16(vf[1][0], pb0, fzero, 0, 0, 0);
            o1 = __builtin_amdgcn_mfma_f32_16x16x32_bf16(vf[1][1], pb1, o1, 0, 0, 0);
            #pragma unroll
            for (int r = 0; r < 4; ++r) { o0[r] *= inv; o1[r] *= inv; }

            // exchange over d axis -> (token = rc*16+lm, d = quad*8..+8)
            bf16x8 ob = xchg32(o0, o1);
            *(bf16x8*)(sX + (rc * 16 + lm) * LDA + h * HD + quad * 8) = ob;  // sO overlay
        }
    }
    __syncthreads();   // attn_out complete

    // ---------- Phase 3: out = attn_out @ wp^T + bp ----------
    {
        const int n0 = wv * HD;
        f32x4 acc[4][2];
        #pragma unroll
        for (int mt = 0; mt < 4; ++mt) { acc[mt][0] = fzero; acc[mt][1] = fzero; }

        #pragma unroll
        for (int ks = 0; ks < 8; ++ks) {
            bf16x8 bfr[2];
            #pragma unroll
            for (int nt = 0; nt < 2; ++nt)
                bfr[nt] = ld16(wp + (n0 + nt * 16 + lm) * CDIM + ks * 32 + quad * 8);
            bf16x8 afr[4];
            #pragma unroll
            for (int mt = 0; mt < 4; ++mt)
                afr[mt] = ld16(sX + (mt * 16 + lm) * LDA + ks * 32 + quad * 8);
            #pragma unroll
            for (int mt = 0; mt < 4; ++mt)
                #pragma unroll
                for (int nt = 0; nt < 2; ++nt)
                    acc[mt][nt] = __builtin_amdgcn_mfma_f32_16x16x32_bf16(afr[mt], bfr[nt], acc[mt][nt], 0, 0, 0);
        }

        float bpv[2] = { bp[n0 + lm], bp[n0 + 16 + lm] };
        #pragma unroll
        for (int mt = 0; mt < 4; ++mt)
            #pragma unroll
            for (int nt = 0; nt < 2; ++nt)
                #pragma unroll
                for (int reg = 0; reg < 4; ++reg) {
                    int r = mt * 16 + quad * 4 + reg;
                    out[((size_t)b * NTOK + r) * CDIM + n0 + nt * 16 + lm] = acc[mt][nt][reg] + bpv[nt];
                }
    }
}

extern "C" void kernel_launch(void* const* d_in, const int* in_sizes, int n_in,
                              void* d_out, int out_size, void* d_ws, size_t ws_size,
                              hipStream_t stream) {
    const float* x    = (const float*)d_in[0];
    const float* mask = (const float*)d_in[1];
    const float* wq   = (const float*)d_in[2];
    const float* bq   = (const float*)d_in[3];
    const float* wp   = (const float*)d_in[4];
    const float* bp   = (const float*)d_in[5];
    const float* bt   = (const float*)d_in[6];

    unsigned short* wqb   = (unsigned short*)d_ws;              // 768x256 bf16
    unsigned short* wpb   = wqb + 196608;                        // 256x256 bf16
    float*          relbQ = (float*)((char*)d_ws + 524288);     // 8x64x64 fp32 (h, q, k)
    float*          out   = (float*)d_out;

    precast_kernel<<<1152, 256, 0, stream>>>(wq, wp, bt, wqb, wpb, relbQ);
    win_attn_kernel<<<NWIN, 512, 0, stream>>>(x, mask, bq, bp, wqb, wpb, relbQ, out);
}

// Round 7
// 421.061 us; speedup vs baseline: 1.3393x; 1.0951x over previous
//
#include <hip/hip_runtime.h>

#define NWIN 2048
#define NTOK 64
#define CDIM 256
#define NH 8
#define HD 32
#define QSCALE 0.17677669529663689f   // 32^-0.5

// LDS stride for x / attn_out tiles (bf16 units): 264 -> row stride 528 B =
// 132 words; 132 mod 32 = 4 -> 2-way on b128 access (free, m136).
#define LDA 264
#define SKW (NH * 4 * 64 * 8)   // K-frag region per window, ushorts (32 KB)

typedef __bf16 bf16x8 __attribute__((ext_vector_type(8)));
typedef float  f32x4  __attribute__((ext_vector_type(4)));
typedef unsigned int u32x4 __attribute__((ext_vector_type(4)));

__device__ __forceinline__ unsigned short f2bf(float f) {
    union { float f; unsigned u; } v; v.f = f;
    unsigned r = v.u + 0x7FFFu + ((v.u >> 16) & 1u);   // RNE
    return (unsigned short)(r >> 16);
}

__device__ __forceinline__ bf16x8 ld16(const unsigned short* p) {
    return *(const bf16x8*)p;
}

__device__ __forceinline__ unsigned cvtpk(float lo, float hi) {
    unsigned r;
    asm("v_cvt_pk_bf16_f32 %0, %1, %2" : "=v"(r) : "v"(lo), "v"(hi));
    return r;
}
__device__ __forceinline__ void pl32(unsigned &a, unsigned &b) {
    asm("v_permlane32_swap_b32 %0, %1" : "+v"(a), "+v"(b));
}
__device__ __forceinline__ void pl16(unsigned &a, unsigned &b) {
    asm("v_permlane16_swap_b32 %0, %1" : "+v"(a), "+v"(b));
}

// In-register C-layout -> A/B-frag exchange over a 32-long axis (verified r1-r6).
__device__ __forceinline__ bf16x8 xchg32(f32x4 t0, f32x4 t1) {
    unsigned u00 = cvtpk(t0[0], t0[1]);
    unsigned u01 = cvtpk(t0[2], t0[3]);
    unsigned u10 = cvtpk(t1[0], t1[1]);
    unsigned u11 = cvtpk(t1[2], t1[3]);
    pl32(u00, u10);
    pl32(u01, u11);
    pl16(u00, u10);
    pl16(u01, u11);
    union { u32x4 u; bf16x8 v; } r;
    r.u = (u32x4){u00, u01, u10, u11};
    return r.v;
}

// ---- precast: weights fp32->bf16; bias_table -> relbQ[h][q][k] fp32 ----
__global__ void precast_kernel(const float* __restrict__ wq, const float* __restrict__ wp,
                               const float* __restrict__ bt,
                               unsigned short* __restrict__ wqb, unsigned short* __restrict__ wpb,
                               float* __restrict__ relbQ) {
    int i = blockIdx.x * 256 + threadIdx.x;
    if (i < 196608) {
        wqb[i] = f2bf(wq[i]);
    } else if (i < 262144) {
        wpb[i - 196608] = f2bf(wp[i - 196608]);
    } else if (i < 294912) {
        int j = i - 262144;            // h*4096 + q*64 + k
        int h = j >> 12;
        int q = (j >> 6) & 63;
        int k = j & 63;
        int yq = q >> 3, xq = q & 7, yk = k >> 3, xk = k & 7;
        int idx = (yq - yk + 7) * 15 + (xq - xk + 7);
        relbQ[j] = bt[idx * NH + h];
    }
}

// 512 threads = 8 waves, wave = head, TWO windows per block (dual-stream ILP).
// Occupancy is capped at 8 waves/CU by the 256-reg tier (r1/r2/r4/r6: the
// 128-reg tier always spills ~GBs of scratch). With TLP capped, each wave
// gets two independent windows: stream B's instructions fill stream A's
// memory stalls. K frags live in LDS (r6 mechanism) to bound persistents.
__global__ __launch_bounds__(512, 2)
void win_attn_kernel(const float* __restrict__ x, const float* __restrict__ mask,
                     const float* __restrict__ bq, const float* __restrict__ bp,
                     const unsigned short* __restrict__ wq, const unsigned short* __restrict__ wp,
                     const float* __restrict__ relbQ, float* __restrict__ out) {
    // 2 x 33,792 B x/attn_out (overlaid) + 2 x 32,768 B K frags = 133,120 B
    __shared__ __align__(16) unsigned short sm[2 * NTOK * LDA + 2 * SKW];

    const int b0   = blockIdx.x * 2;      // windows b0, b0+1
    const int tid  = threadIdx.x;
    const int wv   = tid >> 6;            // wave id == head id
    const int lane = tid & 63;
    const int lm   = lane & 15;
    const int quad = lane >> 4;
    const f32x4 fzero = {0.f, 0.f, 0.f, 0.f};

    // ---------- Phase 0: stage both windows' x, fp32 -> bf16 ----------
    {
        const int row = tid >> 3;             // 64 rows, 8 threads/row
        const int c0  = (tid & 7) * 32;
        #pragma unroll
        for (int w = 0; w < 2; ++w) {
            const float4* gx = (const float4*)(x + ((size_t)(b0 + w) * NTOK + row) * CDIM + c0);
            unsigned short* dst = sm + w * (NTOK * LDA) + row * LDA + c0;
            #pragma unroll
            for (int i = 0; i < 4; ++i) {
                float4 a = gx[2 * i];
                float4 c = gx[2 * i + 1];
                u32x4 v = { cvtpk(a.x, a.y), cvtpk(a.z, a.w), cvtpk(c.x, c.y), cvtpk(c.z, c.w) };
                *(u32x4*)(dst + i * 8) = v;
            }
        }
    }
    __syncthreads();

    const int h = wv;

    // ---------- Phase 1: projections for both windows ----------
    bf16x8 qf[2][4];     // Q B-frags per window
    bf16x8 vf[2][2][2];  // V^T A-frags per window
    #pragma unroll
    for (int w = 0; w < 2; ++w) {
        const unsigned short* sXw = sm + w * (NTOK * LDA);
        unsigned short* sKw = sm + 2 * (NTOK * LDA) + w * SKW;

        // -- K^T = W_k . x^T ; frags straight to LDS --
        {
            f32x4 a0[4], a1[4];
            #pragma unroll
            for (int nt = 0; nt < 4; ++nt) { a0[nt] = fzero; a1[nt] = fzero; }
            const unsigned short* w0 = wq + (CDIM + h*HD + lm) * CDIM;
            const unsigned short* w1 = wq + (CDIM + h*HD + 16 + lm) * CDIM;
            #pragma unroll
            for (int ks = 0; ks < 8; ++ks) {
                bf16x8 xa[4];
                #pragma unroll
                for (int nt = 0; nt < 4; ++nt)
                    xa[nt] = ld16(sXw + (nt * 16 + lm) * LDA + ks * 32 + quad * 8);
                bf16x8 wf0 = ld16(w0 + ks * 32 + quad * 8);
                bf16x8 wf1 = ld16(w1 + ks * 32 + quad * 8);
                #pragma unroll
                for (int nt = 0; nt < 4; ++nt) {
                    a0[nt] = __builtin_amdgcn_mfma_f32_16x16x32_bf16(wf0, xa[nt], a0[nt], 0, 0, 0);
                    a1[nt] = __builtin_amdgcn_mfma_f32_16x16x32_bf16(wf1, xa[nt], a1[nt], 0, 0, 0);
                }
            }
            const float4 bk0 = *(const float4*)(bq + CDIM + h*HD + quad*4);
            const float4 bk1 = *(const float4*)(bq + CDIM + h*HD + 16 + quad*4);
            const float b0v[4] = {bk0.x, bk0.y, bk0.z, bk0.w};
            const float b1v[4] = {bk1.x, bk1.y, bk1.z, bk1.w};
            #pragma unroll
            for (int nt = 0; nt < 4; ++nt) {
                #pragma unroll
                for (int r = 0; r < 4; ++r) { a0[nt][r] += b0v[r]; a1[nt][r] += b1v[r]; }
                bf16x8 kfrag = xchg32(a0[nt], a1[nt]);
                *(bf16x8*)(sKw + ((h * 4 + nt) * 64 + lane) * 8) = kfrag;   // contiguous, conflict-free
            }
        }

        // -- Q^T = W_q . x^T (persistent qf[w]) --
        {
            f32x4 a0[4], a1[4];
            #pragma unroll
            for (int nt = 0; nt < 4; ++nt) { a0[nt] = fzero; a1[nt] = fzero; }
            const unsigned short* w0 = wq + (h*HD + lm) * CDIM;
            const unsigned short* w1 = wq + (h*HD + 16 + lm) * CDIM;
            #pragma unroll
            for (int ks = 0; ks < 8; ++ks) {
                bf16x8 xa[4];
                #pragma unroll
                for (int nt = 0; nt < 4; ++nt)
                    xa[nt] = ld16(sXw + (nt * 16 + lm) * LDA + ks * 32 + quad * 8);
                bf16x8 wf0 = ld16(w0 + ks * 32 + quad * 8);
                bf16x8 wf1 = ld16(w1 + ks * 32 + quad * 8);
                #pragma unroll
                for (int nt = 0; nt < 4; ++nt) {
                    a0[nt] = __builtin_amdgcn_mfma_f32_16x16x32_bf16(wf0, xa[nt], a0[nt], 0, 0, 0);
                    a1[nt] = __builtin_amdgcn_mfma_f32_16x16x32_bf16(wf1, xa[nt], a1[nt], 0, 0, 0);
                }
            }
            const float4 bq0 = *(const float4*)(bq + h*HD + quad*4);
            const float4 bq1 = *(const float4*)(bq + h*HD + 16 + quad*4);
            const float b0v[4] = {bq0.x, bq0.y, bq0.z, bq0.w};
            const float b1v[4] = {bq1.x, bq1.y, bq1.z, bq1.w};
            #pragma unroll
            for (int nt = 0; nt < 4; ++nt) {
                #pragma unroll
                for (int r = 0; r < 4; ++r) {
                    a0[nt][r] = (a0[nt][r] + b0v[r]) * QSCALE;
                    a1[nt][r] = (a1[nt][r] + b1v[r]) * QSCALE;
                }
                qf[w][nt] = xchg32(a0[nt], a1[nt]);
            }
        }

        // -- V = x . Wv^T (wide pass, persistent vf[w]) --
        {
            f32x4 va[4][2];
            #pragma unroll
            for (int mt = 0; mt < 4; ++mt) { va[mt][0] = fzero; va[mt][1] = fzero; }
            #pragma unroll
            for (int ks = 0; ks < 8; ++ks) {
                bf16x8 xa[4], wfv[2];
                #pragma unroll
                for (int mt = 0; mt < 4; ++mt)
                    xa[mt] = ld16(sXw + (mt * 16 + lm) * LDA + ks * 32 + quad * 8);
                #pragma unroll
                for (int t = 0; t < 2; ++t)
                    wfv[t] = ld16(wq + (2*CDIM + h*HD + t*16 + lm) * CDIM + ks * 32 + quad * 8);
                #pragma unroll
                for (int mt = 0; mt < 4; ++mt)
                    #pragma unroll
                    for (int t = 0; t < 2; ++t)
                        va[mt][t] = __builtin_amdgcn_mfma_f32_16x16x32_bf16(xa[mt], wfv[t], va[mt][t], 0, 0, 0);
            }
            const float bV0 = bq[2*CDIM + h*HD + lm];
            const float bV1 = bq[2*CDIM + h*HD + 16 + lm];
            #pragma unroll
            for (int mt = 0; mt < 4; ++mt)
                #pragma unroll
                for (int r = 0; r < 4; ++r) { va[mt][0][r] += bV0; va[mt][1][r] += bV1; }
            #pragma unroll
            for (int t = 0; t < 2; ++t) {
                vf[w][t][0] = xchg32(va[0][t], va[1][t]);   // keys  0..31
                vf[w][t][1] = xchg32(va[2][t], va[3][t]);   // keys 32..63
            }
        }
    }
    __syncthreads();   // all sX reads done (sO overlays sX); sK visible

    // ---------- Phase 2: attention, both windows interleaved per rc ----------
    {
        const float* relh = relbQ + h * (NTOK * NTOK);

        #pragma unroll
        for (int rc = 0; rc < 4; ++rc) {
            // shared rel-bias row chunk (head-dependent, window-independent)
            const float* rrow = relh + (rc * 16 + lm) * 64;
            float4 rb[4];
            #pragma unroll
            for (int jt = 0; jt < 4; ++jt)
                rb[jt] = *(const float4*)(rrow + jt * 16 + quad * 4);

            #pragma unroll
            for (int w = 0; w < 2; ++w) {
                const unsigned short* sKh = sm + 2 * (NTOK * LDA) + w * SKW + h * 4 * 64 * 8;
                unsigned short* sOw = sm + w * (NTOK * LDA);
                const float* mrow = mask + (size_t)(b0 + w) * (NTOK * NTOK) + (rc * 16 + lm) * 64;

                // issue mask loads early; kf LDS loads + MFMAs overlap their latency
                float4 mk[4];
                #pragma unroll
                for (int jt = 0; jt < 4; ++jt)
                    mk[jt] = *(const float4*)(mrow + jt * 16 + quad * 4);

                f32x4 s[4];
                #pragma unroll
                for (int jt = 0; jt < 4; ++jt) {
                    bf16x8 kfr = ld16(sKh + (jt * 64 + lane) * 8);
                    s[jt] = __builtin_amdgcn_mfma_f32_16x16x32_bf16(kfr, qf[w][rc], fzero, 0, 0, 0);
                }

                #pragma unroll
                for (int jt = 0; jt < 4; ++jt) {
                    const float rbv[4] = {rb[jt].x, rb[jt].y, rb[jt].z, rb[jt].w};
                    const float mkv[4] = {mk[jt].x, mk[jt].y, mk[jt].z, mk[jt].w};
                    #pragma unroll
                    for (int r = 0; r < 4; ++r) s[jt][r] += rbv[r] + mkv[r];
                }

                // softmax over keys: in-lane + 2 cross-quad shuffles
                float mx = s[0][0];
                #pragma unroll
                for (int jt = 0; jt < 4; ++jt)
                    #pragma unroll
                    for (int r = 0; r < 4; ++r) mx = fmaxf(mx, s[jt][r]);
                mx = fmaxf(mx, __shfl_xor(mx, 16, 64));
                mx = fmaxf(mx, __shfl_xor(mx, 32, 64));

                float sum = 0.f;
                #pragma unroll
                for (int jt = 0; jt < 4; ++jt)
                    #pragma unroll
                    for (int r = 0; r < 4; ++r) {
                        float e = __expf(s[jt][r] - mx);
                        s[jt][r] = e;
                        sum += e;
                    }
                sum += __shfl_xor(sum, 16, 64);
                sum += __shfl_xor(sum, 32, 64);
                const float inv = 1.0f / sum;   // defer row scaling to PV output

                // P^T B-frags via exchange over key axis
                bf16x8 pb0 = xchg32(s[0], s[1]);   // keys  0..31
                bf16x8 pb1 = xchg32(s[2], s[3]);   // keys 32..63

                // O^T = V^T . P^T
                f32x4 o0 = __builtin_amdgcn_mfma_f32_16x16x32_bf16(vf[w][0][0], pb0, fzero, 0, 0, 0);
                o0 = __builtin_amdgcn_mfma_f32_16x16x32_bf16(vf[w][0][1], pb1, o0, 0, 0, 0);
                f32x4 o1 = __builtin_amdgcn_mfma_f32_16x16x32_bf16(vf[w][1][0], pb0, fzero, 0, 0, 0);
                o1 = __builtin_amdgcn_mfma_f32_16x16x32_bf16(vf[w][1][1], pb1, o1, 0, 0, 0);
                #pragma unroll
                for (int r = 0; r < 4; ++r) { o0[r] *= inv; o1[r] *= inv; }

                // exchange over d axis -> (token = rc*16+lm, d = quad*8..+8)
                bf16x8 ob = xchg32(o0, o1);
                *(bf16x8*)(sOw + (rc * 16 + lm) * LDA + h * HD + quad * 8) = ob;  // sO overlay
            }
        }
    }
    __syncthreads();   // attn_out complete for both windows

    // ---------- Phase 3: out = attn_out @ wp^T + bp, both windows ----------
    {
        const int n0 = wv * HD;
        #pragma unroll
        for (int w = 0; w < 2; ++w) {
            const unsigned short* sOw = sm + w * (NTOK * LDA);
            f32x4 acc[4][2];
            #pragma unroll
            for (int mt = 0; mt < 4; ++mt) { acc[mt][0] = fzero; acc[mt][1] = fzero; }

            #pragma unroll
            for (int ks = 0; ks < 8; ++ks) {
                bf16x8 bfr[2];
                #pragma unroll
                for (int nt = 0; nt < 2; ++nt)
                    bfr[nt] = ld16(wp + (n0 + nt * 16 + lm) * CDIM + ks * 32 + quad * 8);
                bf16x8 afr[4];
                #pragma unroll
                for (int mt = 0; mt < 4; ++mt)
                    afr[mt] = ld16(sOw + (mt * 16 + lm) * LDA + ks * 32 + quad * 8);
                #pragma unroll
                for (int mt = 0; mt < 4; ++mt)
                    #pragma unroll
                    for (int nt = 0; nt < 2; ++nt)
                        acc[mt][nt] = __builtin_amdgcn_mfma_f32_16x16x32_bf16(afr[mt], bfr[nt], acc[mt][nt], 0, 0, 0);
            }

            float bpv[2] = { bp[n0 + lm], bp[n0 + 16 + lm] };
            #pragma unroll
            for (int mt = 0; mt < 4; ++mt)
                #pragma unroll
                for (int nt = 0; nt < 2; ++nt)
                    #pragma unroll
                    for (int reg = 0; reg < 4; ++reg) {
                        int r = mt * 16 + quad * 4 + reg;
                        out[((size_t)(b0 + w) * NTOK + r) * CDIM + n0 + nt * 16 + lm] = acc[mt][nt][reg] + bpv[nt];
                    }
        }
    }
}

extern "C" void kernel_launch(void* const* d_in, const int* in_sizes, int n_in,
                              void* d_out, int out_size, void* d_ws, size_t ws_size,
                              hipStream_t stream) {
    const float* x    = (const float*)d_in[0];
    const float* mask = (const float*)d_in[1];
    const float* wq   = (const float*)d_in[2];
    const float* bq   = (const float*)d_in[3];
    const float* wp   = (const float*)d_in[4];
    const float* bp   = (const float*)d_in[5];
    const float* bt   = (const float*)d_in[6];

    unsigned short* wqb   = (unsigned short*)d_ws;              // 768x256 bf16
    unsigned short* wpb   = wqb + 196608;                        // 256x256 bf16
    float*          relbQ = (float*)((char*)d_ws + 524288);     // 8x64x64 fp32 (h, q, k)
    float*          out   = (float*)d_out;

    precast_kernel<<<1152, 256, 0, stream>>>(wq, wp, bt, wqb, wpb, relbQ);
    win_attn_kernel<<<NWIN / 2, 512, 0, stream>>>(x, mask, bq, bp, wqb, wpb, relbQ, out);
}

// Round 8
// 415.954 us; speedup vs baseline: 1.3558x; 1.0123x over previous
//
#include <hip/hip_runtime.h>

#define NWIN 2048
#define NTOK 64
#define CDIM 256
#define NH 8
#define HD 32
#define QSCALE 0.17677669529663689f   // 32^-0.5

// LDS stride for x / attn_out tiles (bf16 units): 264 -> row stride 528 B =
// 132 words; 132 mod 32 = 4 -> 2-way on b128 access (free, m136).
#define LDA 264
// LDS stride for the mask tile (f32 units): 68 -> 2-way on float4 reads (free).
#define LDM 68

typedef __bf16 bf16x8 __attribute__((ext_vector_type(8)));
typedef float  f32x4  __attribute__((ext_vector_type(4)));
typedef unsigned int u32x4 __attribute__((ext_vector_type(4)));

__device__ __forceinline__ unsigned short f2bf(float f) {
    union { float f; unsigned u; } v; v.f = f;
    unsigned r = v.u + 0x7FFFu + ((v.u >> 16) & 1u);   // RNE
    return (unsigned short)(r >> 16);
}

__device__ __forceinline__ bf16x8 ld16(const unsigned short* p) {
    return *(const bf16x8*)p;
}

__device__ __forceinline__ unsigned cvtpk(float lo, float hi) {
    unsigned r;
    asm("v_cvt_pk_bf16_f32 %0, %1, %2" : "=v"(r) : "v"(lo), "v"(hi));
    return r;
}
__device__ __forceinline__ void pl32(unsigned &a, unsigned &b) {
    asm("v_permlane32_swap_b32 %0, %1" : "+v"(a), "+v"(b));
}
__device__ __forceinline__ void pl16(unsigned &a, unsigned &b) {
    asm("v_permlane16_swap_b32 %0, %1" : "+v"(a), "+v"(b));
}

// In-register C-layout -> A/B-frag exchange over a 32-long axis (verified r1-r7).
__device__ __forceinline__ bf16x8 xchg32(f32x4 t0, f32x4 t1) {
    unsigned u00 = cvtpk(t0[0], t0[1]);
    unsigned u01 = cvtpk(t0[2], t0[3]);
    unsigned u10 = cvtpk(t1[0], t1[1]);
    unsigned u11 = cvtpk(t1[2], t1[3]);
    pl32(u00, u10);
    pl32(u01, u11);
    pl16(u00, u10);
    pl16(u01, u11);
    union { u32x4 u; bf16x8 v; } r;
    r.u = (u32x4){u00, u01, u10, u11};
    return r.v;
}

// ---- precast: weights fp32->bf16; bias_table -> relbQ[h][q][k] fp32 ----
__global__ void precast_kernel(const float* __restrict__ wq, const float* __restrict__ wp,
                               const float* __restrict__ bt,
                               unsigned short* __restrict__ wqb, unsigned short* __restrict__ wpb,
                               float* __restrict__ relbQ) {
    int i = blockIdx.x * 256 + threadIdx.x;
    if (i < 196608) {
        wqb[i] = f2bf(wq[i]);
    } else if (i < 262144) {
        wpb[i - 196608] = f2bf(wp[i - 196608]);
    } else if (i < 294912) {
        int j = i - 262144;            // h*4096 + q*64 + k
        int h = j >> 12;
        int q = (j >> 6) & 63;
        int k = j & 63;
        int yq = q >> 3, xq = q & 7, yk = k >> 3, xk = k & 7;
        int idx = (yq - yk + 7) * 15 + (xq - xk + 7);
        relbQ[j] = bt[idx * NH + h];
    }
}

// I$-footprint experiment (r8): all multi-iteration loops ROLLED
// (#pragma unroll 1). r0/r3/r7 were fully unrolled (~50-80 KB of code vs
// 32 KB I$) and all landed at ~31 us*CU per window regardless of occupancy
// or ILP -- consistent with instruction-fetch thrash stalling all waves.
// Q frags go to LDS so the rolled rc-loop never runtime-indexes a register
// array (rule #20); K/V frags stay in registers.
__global__ __launch_bounds__(512, 2)
void win_attn_kernel(const float* __restrict__ x, const float* __restrict__ mask,
                     const float* __restrict__ bq, const float* __restrict__ bp,
                     const unsigned short* __restrict__ wq, const unsigned short* __restrict__ wp,
                     const float* __restrict__ relbQ, float* __restrict__ out) {
    // sX/sO overlay 33,792 B + sM 17,408 B + sQ 32,768 B = 83,968 B
    __shared__ __align__(16) unsigned char smraw[83968];
    unsigned short* sX = (unsigned short*)smraw;          // x during phase 1; attn_out after
    float*          sM = (float*)(smraw + 33792);         // mask (f32), stride LDM
    unsigned short* sQ = (unsigned short*)(smraw + 51200);// Q frags: [(h*4+rc)*64+lane]*8

    const int b    = blockIdx.x;
    const int tid  = threadIdx.x;
    const int wv   = tid >> 6;            // wave id == head id
    const int lane = tid & 63;
    const int lm   = lane & 15;
    const int quad = lane >> 4;
    const f32x4 fzero = {0.f, 0.f, 0.f, 0.f};

    // ---------- Phase 0: stage x (fp32->bf16) and mask into LDS ----------
    {
        const int row = tid >> 3;             // 64 rows, 8 threads/row
        const int c0  = (tid & 7) * 32;
        const float4* gx = (const float4*)(x + ((size_t)b * NTOK + row) * CDIM + c0);
        unsigned short* dst = sX + row * LDA + c0;
        #pragma unroll 1
        for (int i = 0; i < 4; ++i) {
            float4 a = gx[2 * i];
            float4 c = gx[2 * i + 1];
            u32x4 w = { cvtpk(a.x, a.y), cvtpk(a.z, a.w), cvtpk(c.x, c.y), cvtpk(c.z, c.w) };
            *(u32x4*)(dst + i * 8) = w;
        }
        const int mc0 = (tid & 7) * 8;
        const float4* gm = (const float4*)(mask + (size_t)b * (NTOK * NTOK) + row * 64 + mc0);
        float4 m0 = gm[0], m1 = gm[1];
        *(float4*)(sM + row * LDM + mc0)     = m0;
        *(float4*)(sM + row * LDM + mc0 + 4) = m1;
    }
    __syncthreads();

    const int h = wv;

    // ---------- Phase 1a: K^T = W_k . x^T -> persistent kf[4] ----------
    bf16x8 kf[4];
    {
        f32x4 a0[4], a1[4];
        #pragma unroll
        for (int nt = 0; nt < 4; ++nt) { a0[nt] = fzero; a1[nt] = fzero; }
        const unsigned short* w0 = wq + (CDIM + h*HD + lm) * CDIM;
        const unsigned short* w1 = wq + (CDIM + h*HD + 16 + lm) * CDIM;
        #pragma unroll 1
        for (int ks = 0; ks < 8; ++ks) {
            bf16x8 xa[4];
            #pragma unroll
            for (int nt = 0; nt < 4; ++nt)
                xa[nt] = ld16(sX + (nt * 16 + lm) * LDA + ks * 32 + quad * 8);
            bf16x8 wf0 = ld16(w0 + ks * 32 + quad * 8);
            bf16x8 wf1 = ld16(w1 + ks * 32 + quad * 8);
            #pragma unroll
            for (int nt = 0; nt < 4; ++nt) {
                a0[nt] = __builtin_amdgcn_mfma_f32_16x16x32_bf16(wf0, xa[nt], a0[nt], 0, 0, 0);
                a1[nt] = __builtin_amdgcn_mfma_f32_16x16x32_bf16(wf1, xa[nt], a1[nt], 0, 0, 0);
            }
        }
        const float4 b0 = *(const float4*)(bq + CDIM + h*HD + quad*4);
        const float4 b1 = *(const float4*)(bq + CDIM + h*HD + 16 + quad*4);
        const float b0v[4] = {b0.x, b0.y, b0.z, b0.w};
        const float b1v[4] = {b1.x, b1.y, b1.z, b1.w};
        #pragma unroll
        for (int nt = 0; nt < 4; ++nt) {
            #pragma unroll
            for (int r = 0; r < 4; ++r) { a0[nt][r] += b0v[r]; a1[nt][r] += b1v[r]; }
            kf[nt] = xchg32(a0[nt], a1[nt]);
        }
    }

    // ---------- Phase 1b: Q^T = W_q . x^T -> frags to LDS (sQ) ----------
    {
        f32x4 a0[4], a1[4];
        #pragma unroll
        for (int nt = 0; nt < 4; ++nt) { a0[nt] = fzero; a1[nt] = fzero; }
        const unsigned short* w0 = wq + (h*HD + lm) * CDIM;
        const unsigned short* w1 = wq + (h*HD + 16 + lm) * CDIM;
        #pragma unroll 1
        for (int ks = 0; ks < 8; ++ks) {
            bf16x8 xa[4];
            #pragma unroll
            for (int nt = 0; nt < 4; ++nt)
                xa[nt] = ld16(sX + (nt * 16 + lm) * LDA + ks * 32 + quad * 8);
            bf16x8 wf0 = ld16(w0 + ks * 32 + quad * 8);
            bf16x8 wf1 = ld16(w1 + ks * 32 + quad * 8);
            #pragma unroll
            for (int nt = 0; nt < 4; ++nt) {
                a0[nt] = __builtin_amdgcn_mfma_f32_16x16x32_bf16(wf0, xa[nt], a0[nt], 0, 0, 0);
                a1[nt] = __builtin_amdgcn_mfma_f32_16x16x32_bf16(wf1, xa[nt], a1[nt], 0, 0, 0);
            }
        }
        const float4 b0 = *(const float4*)(bq + h*HD + quad*4);
        const float4 b1 = *(const float4*)(bq + h*HD + 16 + quad*4);
        const float b0v[4] = {b0.x, b0.y, b0.z, b0.w};
        const float b1v[4] = {b1.x, b1.y, b1.z, b1.w};
        #pragma unroll
        for (int nt = 0; nt < 4; ++nt) {
            #pragma unroll
            for (int r = 0; r < 4; ++r) {
                a0[nt][r] = (a0[nt][r] + b0v[r]) * QSCALE;
                a1[nt][r] = (a1[nt][r] + b1v[r]) * QSCALE;
            }
            bf16x8 qfrag = xchg32(a0[nt], a1[nt]);
            *(bf16x8*)(sQ + ((h * 4 + nt) * 64 + lane) * 8) = qfrag;   // own-wave data
        }
    }

    // ---------- Phase 1c: V = x . Wv^T -> persistent vf[2][2] ----------
    bf16x8 vf[2][2];
    {
        f32x4 va[4][2];
        #pragma unroll
        for (int mt = 0; mt < 4; ++mt) { va[mt][0] = fzero; va[mt][1] = fzero; }
        const unsigned short* wv0 = wq + (2*CDIM + h*HD + lm) * CDIM;
        const unsigned short* wv1 = wq + (2*CDIM + h*HD + 16 + lm) * CDIM;
        #pragma unroll 1
        for (int ks = 0; ks < 8; ++ks) {
            bf16x8 xa[4];
            #pragma unroll
            for (int mt = 0; mt < 4; ++mt)
                xa[mt] = ld16(sX + (mt * 16 + lm) * LDA + ks * 32 + quad * 8);
            bf16x8 wfv0 = ld16(wv0 + ks * 32 + quad * 8);
            bf16x8 wfv1 = ld16(wv1 + ks * 32 + quad * 8);
            #pragma unroll
            for (int mt = 0; mt < 4; ++mt) {
                va[mt][0] = __builtin_amdgcn_mfma_f32_16x16x32_bf16(xa[mt], wfv0, va[mt][0], 0, 0, 0);
                va[mt][1] = __builtin_amdgcn_mfma_f32_16x16x32_bf16(xa[mt], wfv1, va[mt][1], 0, 0, 0);
            }
        }
        const float bV0 = bq[2*CDIM + h*HD + lm];
        const float bV1 = bq[2*CDIM + h*HD + 16 + lm];
        #pragma unroll
        for (int mt = 0; mt < 4; ++mt)
            #pragma unroll
            for (int r = 0; r < 4; ++r) { va[mt][0][r] += bV0; va[mt][1][r] += bV1; }
        vf[0][0] = xchg32(va[0][0], va[1][0]);   // d 0..15,  keys  0..31
        vf[0][1] = xchg32(va[2][0], va[3][0]);   // d 0..15,  keys 32..63
        vf[1][0] = xchg32(va[0][1], va[1][1]);   // d 16..31, keys  0..31
        vf[1][1] = xchg32(va[2][1], va[3][1]);   // d 16..31, keys 32..63
    }
    __syncthreads();   // all sX reads done (sO overlays sX); sQ visible

    // ---------- Phase 2: attention, rc loop ROLLED ----------
    {
        const float* relh = relbQ + h * (NTOK * NTOK);
        const unsigned short* sQh = sQ + h * 4 * 64 * 8;

        #pragma unroll 1
        for (int rc = 0; rc < 4; ++rc) {
            bf16x8 qa = ld16(sQh + (rc * 64 + lane) * 8);
            f32x4 s[4];
            #pragma unroll
            for (int jt = 0; jt < 4; ++jt)
                s[jt] = __builtin_amdgcn_mfma_f32_16x16x32_bf16(kf[jt], qa, fzero, 0, 0, 0);

            const float* mrow = sM   + (rc * 16 + lm) * LDM;
            const float* rrow = relh + (rc * 16 + lm) * 64;
            #pragma unroll
            for (int jt = 0; jt < 4; ++jt) {
                float4 rb = *(const float4*)(rrow + jt * 16 + quad * 4);
                float4 mk = *(const float4*)(mrow + jt * 16 + quad * 4);
                const float rbv[4] = {rb.x, rb.y, rb.z, rb.w};
                const float mkv[4] = {mk.x, mk.y, mk.z, mk.w};
                #pragma unroll
                for (int r = 0; r < 4; ++r) s[jt][r] += rbv[r] + mkv[r];
            }

            // softmax over keys: in-lane + 2 cross-quad shuffles
            float mx = s[0][0];
            #pragma unroll
            for (int jt = 0; jt < 4; ++jt)
                #pragma unroll
                for (int r = 0; r < 4; ++r) mx = fmaxf(mx, s[jt][r]);
            mx = fmaxf(mx, __shfl_xor(mx, 16, 64));
            mx = fmaxf(mx, __shfl_xor(mx, 32, 64));

            float sum = 0.f;
            #pragma unroll
            for (int jt = 0; jt < 4; ++jt)
                #pragma unroll
                for (int r = 0; r < 4; ++r) {
                    float e = __expf(s[jt][r] - mx);
                    s[jt][r] = e;
                    sum += e;
                }
            sum += __shfl_xor(sum, 16, 64);
            sum += __shfl_xor(sum, 32, 64);
            const float inv = 1.0f / sum;   // defer row scaling to PV output

            // P^T B-frags via exchange over key axis
            bf16x8 pb0 = xchg32(s[0], s[1]);   // keys  0..31
            bf16x8 pb1 = xchg32(s[2], s[3]);   // keys 32..63

            // O^T = V^T . P^T
            f32x4 o0 = __builtin_amdgcn_mfma_f32_16x16x32_bf16(vf[0][0], pb0, fzero, 0, 0, 0);
            o0 = __builtin_amdgcn_mfma_f32_16x16x32_bf16(vf[0][1], pb1, o0, 0, 0, 0);
            f32x4 o1 = __builtin_amdgcn_mfma_f32_16x16x32_bf16(vf[1][0], pb0, fzero, 0, 0, 0);
            o1 = __builtin_amdgcn_mfma_f32_16x16x32_bf16(vf[1][1], pb1, o1, 0, 0, 0);
            #pragma unroll
            for (int r = 0; r < 4; ++r) { o0[r] *= inv; o1[r] *= inv; }

            // exchange over d axis -> (token = rc*16+lm, d = quad*8..+8)
            bf16x8 ob = xchg32(o0, o1);
            *(bf16x8*)(sX + (rc * 16 + lm) * LDA + h * HD + quad * 8) = ob;  // sO overlay
        }
    }
    __syncthreads();   // attn_out complete

    // ---------- Phase 3: out = attn_out @ wp^T + bp, ks loop ROLLED ----------
    {
        const int n0 = wv * HD;
        f32x4 acc[4][2];
        #pragma unroll
        for (int mt = 0; mt < 4; ++mt) { acc[mt][0] = fzero; acc[mt][1] = fzero; }
        const unsigned short* wp0 = wp + (n0 + lm) * CDIM;
        const unsigned short* wp1 = wp + (n0 + 16 + lm) * CDIM;

        #pragma unroll 1
        for (int ks = 0; ks < 8; ++ks) {
            bf16x8 bfr0 = ld16(wp0 + ks * 32 + quad * 8);
            bf16x8 bfr1 = ld16(wp1 + ks * 32 + quad * 8);
            bf16x8 afr[4];
            #pragma unroll
            for (int mt = 0; mt < 4; ++mt)
                afr[mt] = ld16(sX + (mt * 16 + lm) * LDA + ks * 32 + quad * 8);
            #pragma unroll
            for (int mt = 0; mt < 4; ++mt) {
                acc[mt][0] = __builtin_amdgcn_mfma_f32_16x16x32_bf16(afr[mt], bfr0, acc[mt][0], 0, 0, 0);
                acc[mt][1] = __builtin_amdgcn_mfma_f32_16x16x32_bf16(afr[mt], bfr1, acc[mt][1], 0, 0, 0);
            }
        }

        float bpv[2] = { bp[n0 + lm], bp[n0 + 16 + lm] };
        #pragma unroll
        for (int mt = 0; mt < 4; ++mt)
            #pragma unroll
            for (int nt = 0; nt < 2; ++nt)
                #pragma unroll
                for (int reg = 0; reg < 4; ++reg) {
                    int r = mt * 16 + quad * 4 + reg;
                    out[((size_t)b * NTOK + r) * CDIM + n0 + nt * 16 + lm] = acc[mt][nt][reg] + bpv[nt];
                }
    }
}

extern "C" void kernel_launch(void* const* d_in, const int* in_sizes, int n_in,
                              void* d_out, int out_size, void* d_ws, size_t ws_size,
                              hipStream_t stream) {
    const float* x    = (const float*)d_in[0];
    const float* mask = (const float*)d_in[1];
    const float* wq   = (const float*)d_in[2];
    const float* bq   = (const float*)d_in[3];
    const float* wp   = (const float*)d_in[4];
    const float* bp   = (const float*)d_in[5];
    const float* bt   = (const float*)d_in[6];

    unsigned short* wqb   = (unsigned short*)d_ws;              // 768x256 bf16
    unsigned short* wpb   = wqb + 196608;                        // 256x256 bf16
    float*          relbQ = (float*)((char*)d_ws + 524288);     // 8x64x64 fp32 (h, q, k)
    float*          out   = (float*)d_out;

    precast_kernel<<<1152, 256, 0, stream>>>(wq, wp, bt, wqb, wpb, relbQ);
    win_attn_kernel<<<NWIN, 512, 0, stream>>>(x, mask, bq, bp, wqb, wpb, relbQ, out);
}